// Round 9
// baseline (249.751 us; speedup 1.0000x reference)
//
#include <hip/hip_runtime.h>
#include <math.h>

// Problem constants
#define B    2
#define CIN  64
#define LIN  8192
#define L    2048
#define D    128
#define DI   256
#define NS   16
#define RK   8
#define NSTREAM 4        // (dir, batch): s = dir*2 + b
#define CH   32          // tokens per chunk/block
#define NCH  (L/CH)      // 64 chunks per stream
#define TOK  (NSTREAM*L) // 8192
#define SZ_D ((size_t)TOK*D)     // 1,048,576 floats
#define SZ_DI ((size_t)TOK*DI)   // 2,097,152 floats
// LDS row strides (ushorts): start-bank pattern (12r+4q)%32 -> conflict-free b128
#define SXM 280
#define SHN 152

typedef short  bfrag __attribute__((ext_vector_type(8)));
typedef float  facc  __attribute__((ext_vector_type(4)));
#define MFMA __builtin_amdgcn_mfma_f32_16x16x32_bf16

__device__ __forceinline__ float sigmoidf_(float x){ return 1.f/(1.f+__expf(-x)); }
__device__ __forceinline__ float siluf_(float x){ return x*sigmoidf_(x); }
__device__ __forceinline__ ushort f2bf(float f){
    unsigned u = __float_as_uint(f);
    u += 0x7fffu + ((u>>16)&1u);
    return (ushort)(u>>16);
}
__device__ __forceinline__ float bf2f(ushort u){ return __uint_as_float(((unsigned)u)<<16); }
__device__ __forceinline__ float softplusf_(float t){
    return (t > 20.f) ? t : __logf(1.f + __expf(t));
}

// ---------------- fused downsample + weight conversion (proven round 4)
__global__ void __launch_bounds__(256,1)
k_downcvt(const float* __restrict__ x, const float* __restrict__ convd_w,
          const float* __restrict__ bias,
          const float* __restrict__ ipw, const float* __restrict__ opw,
          const float* __restrict__ xpw,
          float* __restrict__ h, ushort* __restrict__ wall){
    int tid = threadIdx.x;
    if (blockIdx.x >= 128){
        int g = (blockIdx.x - 128)*256 + tid;
        for (int i = g; i < 688128; i += 32768){
            ushort v;
            if (i < 393216)      v = f2bf(ipw[i]);
            else if (i < 589824) v = f2bf(opw[i-393216]);
            else {
                int t = i - 589824;
                int k = t & 255, nr = (t>>8) & 63, jj = t>>14;
                v = (nr < 40) ? f2bf(xpw[((size_t)jj*40 + nr)*256 + k]) : (ushort)0;
            }
            wall[i] = v;
        }
        return;
    }
    __shared__ ushort sxd[64*SXM];
    __shared__ ushort swt[64*SXM];
    int mb = blockIdx.x & 63, nb = blockIdx.x >> 6;
    int m0 = mb*64;
    int b = m0 >> 11;
    int l0 = m0 & 2047;
    for (int idx = tid; idx < 64*64; idx += 256){
        int t = idx & 63, cc = idx >> 6;
        float4 v = *(const float4*)(x + ((size_t)(b*CIN + cc))*LIN + 4*(l0+t));
        ushort4 o; o.x=f2bf(v.x); o.y=f2bf(v.y); o.z=f2bf(v.z); o.w=f2bf(v.w);
        *(ushort4*)&sxd[t*SXM + cc*4] = o;
    }
    for (int idx = tid; idx < 64*64; idx += 256){
        int cl = idx >> 6, kq = idx & 63;
        float4 v = *(const float4*)(convd_w + ((size_t)(nb*64 + cl))*256 + kq*4);
        ushort4 o; o.x=f2bf(v.x); o.y=f2bf(v.y); o.z=f2bf(v.z); o.w=f2bf(v.w);
        *(ushort4*)&swt[cl*SXM + kq*4] = o;
    }
    __syncthreads();
    int w = tid>>6, lane = tid&63, rw = w>>1, cw_ = w&1;
    int q = lane>>4, r = lane&15;
    int n0 = nb*64 + cw_*32;
    facc acc[2][2] = {};
    #pragma unroll
    for (int kb=0; kb<8; ++kb){
        bfrag a0 = *(bfrag*)&sxd[(rw*32 + r)*SXM + kb*32 + q*8];
        bfrag a1 = *(bfrag*)&sxd[(rw*32 + 16 + r)*SXM + kb*32 + q*8];
        bfrag b0 = *(bfrag*)&swt[(cw_*32 + r)*SXM + kb*32 + q*8];
        bfrag b1 = *(bfrag*)&swt[(cw_*32 + 16 + r)*SXM + kb*32 + q*8];
        acc[0][0] = MFMA(a0,b0,acc[0][0],0,0,0);
        acc[0][1] = MFMA(a0,b1,acc[0][1],0,0,0);
        acc[1][0] = MFMA(a1,b0,acc[1][0],0,0,0);
        acc[1][1] = MFMA(a1,b1,acc[1][1],0,0,0);
    }
    #pragma unroll
    for (int im=0; im<2; ++im)
    #pragma unroll
    for (int in=0; in<2; ++in){
        int col = n0 + in*16 + r;
        float bv = bias[col];
        #pragma unroll
        for (int r2=0; r2<4; ++r2){
            int row = m0 + rw*32 + im*16 + q*4 + r2;
            int bb = row >> 11, l = row & 2047;
            float v = siluf_(acc[im][in][r2] + bv);
            h[((size_t)(bb*L + l))*D + col] = v;
            h[((size_t)((2+bb)*L + (L-1-l)))*D + col] = v;
        }
    }
}

// ---------------- k_head: LN + in_proj + conv + x_proj + scan1, per 32-token chunk
// grid 256, block 256. Occupancy is grid-limited (1 block/CU) -> register hoists are free.
__global__ void __launch_bounds__(256,1)
k_head(const float* __restrict__ rIn,
       const float* __restrict__ lnw, const float* __restrict__ lnb,
       const ushort* __restrict__ wbi, const ushort* __restrict__ wbx,
       const float* __restrict__ cw, const float* __restrict__ cb,
       const float* __restrict__ Wdt, const float* __restrict__ bdt,
       const float* __restrict__ A_log,
       ushort* __restrict__ zh, ushort* __restrict__ xch,
       float* __restrict__ dtr, float* __restrict__ Bc, float* __restrict__ Cc,
       float* __restrict__ Ap, float* __restrict__ Bp, int blk){
    __shared__ ushort smHn[35*SHN];   // LN out: rows 0..31 owned, 32..34 halo
    __shared__ ushort smXm[35*SXM];   // xm bf16 (rows 32..34 = halo)
    __shared__ ushort smXc[32*SXM];   // conv out bf16
    __shared__ float  smDbc[32*68];   // xproj out
    const int tid = threadIdx.x;
    const int bi = blockIdx.x;
    const int s = bi >> 6, c = bi & 63;
    const int j = (s>>1)*3 + blk;
    const int base_tok = s*L + c*CH;

    // ---- hoisted per-thread params (latency overlaps LN/in_proj phases) ----
    float Ah[NS], wv[RK];
    {
        const float* ar = A_log + ((size_t)j*DI + tid)*NS;
        #pragma unroll
        for (int n=0;n<NS;++n) Ah[n] = ar[n];
        const float* wr = Wdt + ((size_t)j*DI + tid)*RK;
        #pragma unroll
        for (int r=0;r<RK;++r) wv[r] = wr[r];
    }
    const float bb2 = bdt[j*DI + tid];
    float cw0, cw1, cw2, cw3, cbb;
    {
        const float* w4 = cw + ((size_t)j*DI + tid)*4;
        cw0=w4[0]; cw1=w4[1]; cw2=w4[2]; cw3=w4[3];
        cbb = cb[j*DI + tid];
    }
    // ---- hoisted x_proj weight fragments (consumed after conv; loads hide under LN+in_proj) ----
    bfrag wX[8];
    {
        int w = tid>>6, lane = tid&63, q = lane>>4, r = lane&15;
        const ushort* bp = wbx + ((size_t)j*64 + w*16 + r)*256 + q*8;
        #pragma unroll
        for (int kb=0; kb<8; ++kb) wX[kb] = *(const bfrag*)(bp + kb*32);
    }

    // ---- LN (owned 32 tokens; 8 lanes/token; single-buffer read, no write) ----
    {
        int t = tid >> 3, g8 = tid & 7;
        size_t off = (size_t)(base_tok + t)*D + g8*16;
        float4 v[4];
        const float4* cp = (const float4*)(rIn + off);
        #pragma unroll
        for (int i=0;i<4;++i) v[i] = cp[i];
        float s1=0.f, s2=0.f;
        #pragma unroll
        for (int i=0;i<4;++i){
            s1 += v[i].x+v[i].y+v[i].z+v[i].w;
            s2 += v[i].x*v[i].x+v[i].y*v[i].y+v[i].z*v[i].z+v[i].w*v[i].w;
        }
        s1 += __shfl_xor(s1,1); s2 += __shfl_xor(s2,1);
        s1 += __shfl_xor(s1,2); s2 += __shfl_xor(s2,2);
        s1 += __shfl_xor(s1,4); s2 += __shfl_xor(s2,4);
        float mean = s1*(1.f/128.f);
        float var  = s2*(1.f/128.f) - mean*mean;
        float rstd = rsqrtf(var + 1e-5f);
        const float4* lwp = (const float4*)(lnw + j*D + g8*16);
        const float4* lbp = (const float4*)(lnb + j*D + g8*16);
        #pragma unroll
        for (int i=0;i<4;++i){
            float4 lw = lwp[i], lb = lbp[i];
            ushort4 o;
            o.x = f2bf((v[i].x-mean)*rstd*lw.x + lb.x);
            o.y = f2bf((v[i].y-mean)*rstd*lw.y + lb.y);
            o.z = f2bf((v[i].z-mean)*rstd*lw.z + lb.z);
            o.w = f2bf((v[i].w-mean)*rstd*lw.w + lb.w);
            *(ushort4*)&smHn[t*SHN + g8*16 + i*4] = o;
        }
    }
    // ---- halo LN (3 tokens, threads 0..23) ----
    if (c > 0 && tid < 24){
        int t = tid >> 3, g8 = tid & 7;
        size_t off = (size_t)(base_tok - 3 + t)*D + g8*16;
        float4 v[4];
        const float4* cp = (const float4*)(rIn + off);
        #pragma unroll
        for (int i=0;i<4;++i) v[i] = cp[i];
        float s1=0.f, s2=0.f;
        #pragma unroll
        for (int i=0;i<4;++i){
            s1 += v[i].x+v[i].y+v[i].z+v[i].w;
            s2 += v[i].x*v[i].x+v[i].y*v[i].y+v[i].z*v[i].z+v[i].w*v[i].w;
        }
        s1 += __shfl_xor(s1,1); s2 += __shfl_xor(s2,1);
        s1 += __shfl_xor(s1,2); s2 += __shfl_xor(s2,2);
        s1 += __shfl_xor(s1,4); s2 += __shfl_xor(s2,4);
        float mean = s1*(1.f/128.f);
        float var  = s2*(1.f/128.f) - mean*mean;
        float rstd = rsqrtf(var + 1e-5f);
        const float4* lwp = (const float4*)(lnw + j*D + g8*16);
        const float4* lbp = (const float4*)(lnb + j*D + g8*16);
        #pragma unroll
        for (int i=0;i<4;++i){
            float4 lw = lwp[i], lb = lbp[i];
            ushort4 o;
            o.x = f2bf((v[i].x-mean)*rstd*lw.x + lb.x);
            o.y = f2bf((v[i].y-mean)*rstd*lw.y + lb.y);
            o.z = f2bf((v[i].z-mean)*rstd*lw.z + lb.z);
            o.w = f2bf((v[i].w-mean)*rstd*lw.w + lb.w);
            *(ushort4*)&smHn[(32+t)*SHN + g8*16 + i*4] = o;
        }
    }
    __syncthreads();

    // ---- in_proj GEMM: M=48 (rows 32..47 halo tile, 3 valid), N=512, K=128; 4 waves x 128 cols ----
    {
        int w = tid>>6, lane = tid&63, q = lane>>4, r = lane&15;
        bfrag a[3][4];
        #pragma unroll
        for (int rt=0; rt<3; ++rt)
        #pragma unroll
        for (int kb=0; kb<4; ++kb)
            a[rt][kb] = *(bfrag*)&smHn[(rt*16 + r)*SHN + kb*32 + q*8];
        #pragma unroll
        for (int ct=0; ct<8; ++ct){
            int n0 = w*128 + ct*16;
            const ushort* bp = wbi + ((size_t)j*512 + n0 + r)*128 + q*8;
            facc a0 = {}, a1 = {}, a2 = {};
            #pragma unroll
            for (int kb=0; kb<4; ++kb){
                bfrag bv = *(const bfrag*)(bp + kb*32);
                a0 = MFMA(a[0][kb], bv, a0, 0,0,0);
                a1 = MFMA(a[1][kb], bv, a1, 0,0,0);
                a2 = MFMA(a[2][kb], bv, a2, 0,0,0);
            }
            int colL = n0 + r;
            if (colL < DI){
                #pragma unroll
                for (int r2=0;r2<4;++r2){
                    int rr = q*4 + r2;
                    smXm[rr*SXM + colL]      = f2bf(a0[r2]);
                    smXm[(16+rr)*SXM + colL] = f2bf(a1[r2]);
                    if (rr < 3) smXm[(32+rr)*SXM + colL] = f2bf(a2[r2]);
                }
            } else {
                int cz = colL - DI;
                #pragma unroll
                for (int r2=0;r2<4;++r2){
                    int rr = q*4 + r2;
                    zh[(size_t)(base_tok + rr)*DI + cz]      = f2bf(a0[r2]);
                    zh[(size_t)(base_tok + 16 + rr)*DI + cz] = f2bf(a1[r2]);
                }
            }
        }
    }
    __syncthreads();

    // ---- conv + silu (thread-per-d); bf16 to LDS + global ----
    {
        float xm1=0.f, xm2=0.f, xm3=0.f;
        if (c > 0){
            xm3 = bf2f(smXm[32*SXM + tid]);   // token -3
            xm2 = bf2f(smXm[33*SXM + tid]);   // token -2
            xm1 = bf2f(smXm[34*SXM + tid]);   // token -1
        }
        #pragma unroll 4
        for (int i=0;i<CH;++i){
            float x0 = bf2f(smXm[i*SXM + tid]);
            float v = siluf_(cbb + cw3*x0 + cw2*xm1 + cw1*xm2 + cw0*xm3);
            ushort vb = f2bf(v);
            smXc[i*SXM + tid] = vb;
            xch[(size_t)(base_tok+i)*DI + tid] = vb;
            xm3 = xm2; xm2 = xm1; xm1 = x0;
        }
    }
    __syncthreads();

    // ---- x_proj GEMM: M=32, N=64(pad40), K=256 (weights pre-hoisted in wX) ----
    {
        int w = tid>>6, lane = tid&63, q = lane>>4, r = lane&15;
        facc a0 = {}, a1 = {};
        #pragma unroll
        for (int kb=0; kb<8; ++kb){
            bfrag av0 = *(bfrag*)&smXc[r*SXM + kb*32 + q*8];
            bfrag av1 = *(bfrag*)&smXc[(16+r)*SXM + kb*32 + q*8];
            a0 = MFMA(av0, wX[kb], a0, 0,0,0);
            a1 = MFMA(av1, wX[kb], a1, 0,0,0);
        }
        int col = w*16 + r;
        #pragma unroll
        for (int r2=0;r2<4;++r2){
            int rr = q*4 + r2;
            smDbc[rr*68 + col]      = a0[r2];
            smDbc[(16+rr)*68 + col] = a1[r2];
            int row0 = base_tok + rr, row1 = base_tok + 16 + rr;
            if      (col < 8){  dtr[(size_t)row0*RK + col] = a0[r2];      dtr[(size_t)row1*RK + col] = a1[r2]; }
            else if (col < 24){ Bc [(size_t)row0*NS + (col-8)] = a0[r2];  Bc [(size_t)row1*NS + (col-8)] = a1[r2]; }
            else if (col < 40){ Cc [(size_t)row0*NS + (col-24)] = a0[r2]; Cc [(size_t)row1*NS + (col-24)] = a1[r2]; }
        }
    }
    __syncthreads();

    // ---- scan1: local chunk summary (thread-per-d); layout [chunk][d][16n] ----
    {
        float A[NS];
        #pragma unroll
        for (int n=0;n<NS;++n) A[n] = -__expf(Ah[n]);
        float ap[NS], hs[NS];
        #pragma unroll
        for (int n=0;n<NS;++n){ ap[n]=1.f; hs[n]=0.f; }
        #pragma unroll 4
        for (int l=0;l<CH;++l){
            float t = bb2;
            #pragma unroll
            for (int r=0;r<RK;++r) t += smDbc[l*68+r]*wv[r];
            float dtv = softplusf_(t);
            float xv  = bf2f(smXc[l*SXM + tid]);
            float dbx = dtv*xv;
            #pragma unroll
            for (int n=0;n<NS;++n){
                float dA = __expf(dtv*A[n]);
                ap[n] *= dA;
                hs[n] = dA*hs[n] + dbx*smDbc[l*68+8+n];
            }
        }
        size_t pb = (size_t)bi*4096 + (size_t)tid*16;
        #pragma unroll
        for (int k4=0;k4<4;++k4){
            float4 av, bv;
            av.x=ap[k4*4+0]; av.y=ap[k4*4+1]; av.z=ap[k4*4+2]; av.w=ap[k4*4+3];
            bv.x=hs[k4*4+0]; bv.y=hs[k4*4+1]; bv.z=hs[k4*4+2]; bv.w=hs[k4*4+3];
            *(float4*)&Ap[pb + k4*4] = av;
            *(float4*)&Bp[pb + k4*4] = bv;
        }
    }
}

// ---------------- scan mid: 4-way split per (stream, nd) lane + shfl stitch (proven round 7)
__global__ void __launch_bounds__(256,1)
k_scanmid(const float* __restrict__ Aprod, float* __restrict__ Bend){
    int g = blockIdx.x*256 + threadIdx.x;
    int q = g & 3;
    int lane2 = g >> 2;                 // 0..16383
    int ss = lane2 >> 12, nd = lane2 & 4095;
    size_t base = (size_t)ss*NCH*4096 + nd;
    float a[16], b[16];
    #pragma unroll
    for (int i=0;i<16;++i){
        a[i] = Aprod[base + (size_t)(q*16+i)*4096];
        b[i] = Bend [base + (size_t)(q*16+i)*4096];
    }
    float Aag = 1.f, Bag = 0.f;
    #pragma unroll
    for (int i=0;i<16;++i){ Bag = a[i]*Bag + b[i]; Aag *= a[i]; }
    int lid = threadIdx.x & 63, gb = lid & ~3;
    float hcar = 0.f;
    #pragma unroll
    for (int pq = 0; pq < 3; ++pq){
        float aA = __shfl(Aag, gb + pq, 64);
        float aB = __shfl(Bag, gb + pq, 64);
        if (pq < q) hcar = aA*hcar + aB;
    }
    #pragma unroll
    for (int i=0;i<16;++i){
        Bend[base + (size_t)(q*16+i)*4096] = hcar;   // carry INTO chunk q*16+i
        hcar = a[i]*hcar + b[i];
    }
}

// ---------------- k_tail: scan2 + gate + out_proj + residual add.
// blk 0/1: rOut = proj + rIn (blk1's rOut IS the out rf/rb region, aliased).
// blk 2:   atomicAdd contribution (proj + rIn) into out0 (harness-zeroed), bwd mirrored.
__global__ void __launch_bounds__(256,1)
k_tail(const float* __restrict__ dtr, const ushort* __restrict__ xch,
       const float* __restrict__ Bc, const float* __restrict__ Cc,
       const float* __restrict__ A_log,
       const float* __restrict__ Wdt, const float* __restrict__ bdt,
       const float* __restrict__ h0, const ushort* __restrict__ zh,
       const float* __restrict__ Dp, const ushort* __restrict__ wbo,
       const float* __restrict__ rIn, float* __restrict__ rOut,
       float* __restrict__ out0, int blk){
    int c = blockIdx.x, s = blockIdx.y; int j = (s>>1)*3 + blk;
    int d = threadIdx.x;
    __shared__ float sB[CH*NS], sC[CH*NS], sdtr[CH*RK];
    __shared__ ushort sg[CH*SXM];
    int base_tok = s*L + c*CH;
    int w = d>>6, lane = d&63, q = lane>>4, r = lane&15;
    // ---- hoisted out_proj weights (16 bfrags; latency hides under scan2) ----
    bfrag wB0[8], wB1[8];
    {
        const ushort* b0p = wbo + ((size_t)j*128 + w*32 + r)*256 + q*8;
        const ushort* b1p = b0p + 16*256;
        #pragma unroll
        for (int kb=0; kb<8; ++kb){
            wB0[kb] = *(const bfrag*)(b0p + kb*32);
            wB1[kb] = *(const bfrag*)(b1p + kb*32);
        }
    }
    // hoisted per-thread params
    float A[NS], wv[RK];
    {
        const float* ar = A_log + ((size_t)j*DI + d)*NS;
        #pragma unroll
        for (int n=0;n<NS;++n) A[n] = ar[n];
        const float* wr = Wdt + ((size_t)j*DI + d)*RK;
        #pragma unroll
        for (int r2=0;r2<RK;++r2) wv[r2] = wr[r2];
    }
    float bb = bdt[j*DI + d];
    float Dpd = Dp[j*DI + d];
    sB[d] = Bc[(size_t)base_tok*NS + d];
    sB[256+d] = Bc[(size_t)base_tok*NS + 256 + d];
    sC[d] = Cc[(size_t)base_tok*NS + d];
    sC[256+d] = Cc[(size_t)base_tok*NS + 256 + d];
    sdtr[d] = dtr[(size_t)base_tok*RK + d];
    #pragma unroll
    for (int n=0;n<NS;++n) A[n] = -__expf(A[n]);
    float hs[NS];
    {
        size_t pb = (size_t)(s*NCH + c)*4096 + (size_t)d*16;
        #pragma unroll
        for (int k4=0;k4<4;++k4){
            float4 v = *(const float4*)&h0[pb + k4*4];
            hs[k4*4+0]=v.x; hs[k4*4+1]=v.y; hs[k4*4+2]=v.z; hs[k4*4+3]=v.w;
        }
    }
    __syncthreads();
    #pragma unroll 4
    for (int l=0;l<CH;++l){
        float t = bb;
        #pragma unroll
        for (int r2=0;r2<RK;++r2) t += sdtr[l*RK+r2]*wv[r2];
        float dtv = softplusf_(t);
        float xv  = bf2f(xch[(size_t)(base_tok+l)*DI + d]);
        float dbx = dtv*xv;
        float p = 0.f;
        #pragma unroll
        for (int n=0;n<NS;++n){
            float dA = __expf(dtv*A[n]);
            hs[n] = dA*hs[n] + dbx*sB[l*NS+n];
            p += hs[n]*sC[l*NS+n];
        }
        float zv = bf2f(zh[(size_t)(base_tok+l)*DI + d]);
        sg[l*SXM + d] = f2bf((p + Dpd*xv)*siluf_(zv));
    }
    __syncthreads();
    // out_proj: M=32 (2 rt), N=128; wave w -> cols [w*32, w*32+32) (weights pre-hoisted)
    facc acc[2][2] = {};
    #pragma unroll
    for (int kb=0; kb<8; ++kb){
        bfrag av0 = *(bfrag*)&sg[r*SXM + kb*32 + q*8];
        bfrag av1 = *(bfrag*)&sg[(16+r)*SXM + kb*32 + q*8];
        acc[0][0] = MFMA(av0,wB0[kb],acc[0][0],0,0,0);
        acc[0][1] = MFMA(av0,wB1[kb],acc[0][1],0,0,0);
        acc[1][0] = MFMA(av1,wB0[kb],acc[1][0],0,0,0);
        acc[1][1] = MFMA(av1,wB1[kb],acc[1][1],0,0,0);
    }
    if (blk < 2){
        #pragma unroll
        for (int rt=0; rt<2; ++rt)
        #pragma unroll
        for (int ct=0; ct<2; ++ct){
            int col = w*32 + ct*16 + r;
            #pragma unroll
            for (int r2=0;r2<4;++r2){
                int row = base_tok + rt*16 + q*4 + r2;
                size_t i0 = (size_t)row*D + col;
                rOut[i0] = acc[rt][ct][r2] + rIn[i0];
            }
        }
    } else {
        int b = s & 1;
        #pragma unroll
        for (int rt=0; rt<2; ++rt)
        #pragma unroll
        for (int ct=0; ct<2; ++ct){
            int col = w*32 + ct*16 + r;
            #pragma unroll
            for (int r2=0;r2<4;++r2){
                int loc = c*CH + rt*16 + q*4 + r2;
                size_t i0 = (size_t)(s*L + loc)*D + col;
                float v = acc[rt][ct][r2] + rIn[i0];
                int ltgt = (s < 2) ? loc : (L-1-loc);
                atomicAdd(&out0[((size_t)(b*D + col))*L + ltgt], v);
            }
        }
    }
}

extern "C" void kernel_launch(void* const* d_in, const int* in_sizes, int n_in,
                              void* d_out, int out_size, void* d_ws, size_t ws_size,
                              hipStream_t stream){
    const float* x         = (const float*)d_in[0];
    const float* convd_w   = (const float*)d_in[1];
    const float* convd_b   = (const float*)d_in[2];
    const float* ln_w      = (const float*)d_in[3];
    const float* ln_b      = (const float*)d_in[4];
    const float* in_proj_w = (const float*)d_in[5];
    const float* conv_w    = (const float*)d_in[6];
    const float* conv_b    = (const float*)d_in[7];
    const float* xproj_w   = (const float*)d_in[8];
    const float* dtproj_w  = (const float*)d_in[9];
    const float* dtproj_b  = (const float*)d_in[10];
    const float* A_log     = (const float*)d_in[11];
    const float* Dparam    = (const float*)d_in[12];
    const float* outproj_w = (const float*)d_in[13];

    float* ws = (float*)d_ws;
    float* h     = ws; ws += SZ_D;   // residual into blk0
    float* r1    = ws; ws += SZ_D;   // residual into blk1 (= proj0 + h)
    ushort* zh   = (ushort*)ws; ws += SZ_DI/2;   // bf16
    ushort* xch  = (ushort*)ws; ws += SZ_DI/2;   // bf16
    float* Ap    = ws; ws += SZ_D;   // [chunk][d][16n] summaries
    float* Bp    = ws; ws += SZ_D;   // summaries -> carries after scanmid
    float* dtr   = ws; ws += (size_t)TOK*RK;
    float* Bcv   = ws; ws += (size_t)TOK*NS;
    float* Ccv   = ws; ws += (size_t)TOK*NS;
    ushort* wall = (ushort*)ws;
    ushort* wbi  = wall;
    ushort* wbo  = wall + 393216;
    ushort* wbx  = wall + 589824;

    // r2 (residual into blk2, == rf/rb output) lives directly in the output buffer.
    float* out0 = (float*)d_out;
    float* r2p  = (float*)d_out + (size_t)2*D*L;

    k_downcvt<<<256, 256, 0, stream>>>(x, convd_w, convd_b, in_proj_w, outproj_w,
                                       xproj_w, h, wall);

    const float* rin[3]  = { h,  r1,  r2p };
    float*       rout[3] = { r1, r2p, nullptr };
    for (int blk = 0; blk < 3; ++blk){
        k_head<<<NSTREAM*NCH, 256, 0, stream>>>(rin[blk], ln_w, ln_b, wbi, wbx,
                                                conv_w, conv_b, dtproj_w, dtproj_b, A_log,
                                                zh, xch, dtr, Bcv, Ccv, Ap, Bp, blk);
        k_scanmid<<<256, 256, 0, stream>>>(Ap, Bp);
        k_tail<<<dim3(NCH, NSTREAM), 256, 0, stream>>>(dtr, xch, Bcv, Ccv, A_log,
                                                       dtproj_w, dtproj_b, Bp, zh,
                                                       Dparam, wbo, rin[blk], rout[blk],
                                                       out0, blk);
    }
}

// Round 11
// 238.973 us; speedup vs baseline: 1.0451x; 1.0451x over previous
//
#include <hip/hip_runtime.h>
#include <math.h>

// Problem constants
#define B    2
#define CIN  64
#define LIN  8192
#define L    2048
#define D    128
#define DI   256
#define NS   16
#define RK   8
#define NSTREAM 4        // (dir, batch): s = dir*2 + b
#define CH   32          // tokens per chunk/block
#define NCH  (L/CH)      // 64 chunks per stream
#define TOK  (NSTREAM*L) // 8192
#define SZ_D ((size_t)TOK*D)     // 1,048,576 floats
#define SZ_DI ((size_t)TOK*DI)   // 2,097,152 floats
// LDS row strides (ushorts): start-bank pattern (12r+4q)%32 -> conflict-free b128
#define SXM 280
#define SHN 152

typedef short  bfrag __attribute__((ext_vector_type(8)));
typedef float  facc  __attribute__((ext_vector_type(4)));
#define MFMA __builtin_amdgcn_mfma_f32_16x16x32_bf16

__device__ __forceinline__ float sigmoidf_(float x){ return 1.f/(1.f+__expf(-x)); }
__device__ __forceinline__ float siluf_(float x){ return x*sigmoidf_(x); }
__device__ __forceinline__ ushort f2bf(float f){
    unsigned u = __float_as_uint(f);
    u += 0x7fffu + ((u>>16)&1u);
    return (ushort)(u>>16);
}
__device__ __forceinline__ float bf2f(ushort u){ return __uint_as_float(((unsigned)u)<<16); }
__device__ __forceinline__ float softplusf_(float t){
    return (t > 20.f) ? t : __logf(1.f + __expf(t));
}

// ---------------- fused downsample + weight conversion (proven round 4)
__global__ void __launch_bounds__(256,1)
k_downcvt(const float* __restrict__ x, const float* __restrict__ convd_w,
          const float* __restrict__ bias,
          const float* __restrict__ ipw, const float* __restrict__ opw,
          const float* __restrict__ xpw,
          float* __restrict__ h, ushort* __restrict__ wall){
    int tid = threadIdx.x;
    if (blockIdx.x >= 128){
        int g = (blockIdx.x - 128)*256 + tid;
        for (int i = g; i < 688128; i += 32768){
            ushort v;
            if (i < 393216)      v = f2bf(ipw[i]);
            else if (i < 589824) v = f2bf(opw[i-393216]);
            else {
                int t = i - 589824;
                int k = t & 255, nr = (t>>8) & 63, jj = t>>14;
                v = (nr < 40) ? f2bf(xpw[((size_t)jj*40 + nr)*256 + k]) : (ushort)0;
            }
            wall[i] = v;
        }
        return;
    }
    __shared__ ushort sxd[64*SXM];
    __shared__ ushort swt[64*SXM];
    int mb = blockIdx.x & 63, nb = blockIdx.x >> 6;
    int m0 = mb*64;
    int b = m0 >> 11;
    int l0 = m0 & 2047;
    for (int idx = tid; idx < 64*64; idx += 256){
        int t = idx & 63, cc = idx >> 6;
        float4 v = *(const float4*)(x + ((size_t)(b*CIN + cc))*LIN + 4*(l0+t));
        ushort4 o; o.x=f2bf(v.x); o.y=f2bf(v.y); o.z=f2bf(v.z); o.w=f2bf(v.w);
        *(ushort4*)&sxd[t*SXM + cc*4] = o;
    }
    for (int idx = tid; idx < 64*64; idx += 256){
        int cl = idx >> 6, kq = idx & 63;
        float4 v = *(const float4*)(convd_w + ((size_t)(nb*64 + cl))*256 + kq*4);
        ushort4 o; o.x=f2bf(v.x); o.y=f2bf(v.y); o.z=f2bf(v.z); o.w=f2bf(v.w);
        *(ushort4*)&swt[cl*SXM + kq*4] = o;
    }
    __syncthreads();
    int w = tid>>6, lane = tid&63, rw = w>>1, cw_ = w&1;
    int q = lane>>4, r = lane&15;
    int n0 = nb*64 + cw_*32;
    facc acc[2][2] = {};
    #pragma unroll
    for (int kb=0; kb<8; ++kb){
        bfrag a0 = *(bfrag*)&sxd[(rw*32 + r)*SXM + kb*32 + q*8];
        bfrag a1 = *(bfrag*)&sxd[(rw*32 + 16 + r)*SXM + kb*32 + q*8];
        bfrag b0 = *(bfrag*)&swt[(cw_*32 + r)*SXM + kb*32 + q*8];
        bfrag b1 = *(bfrag*)&swt[(cw_*32 + 16 + r)*SXM + kb*32 + q*8];
        acc[0][0] = MFMA(a0,b0,acc[0][0],0,0,0);
        acc[0][1] = MFMA(a0,b1,acc[0][1],0,0,0);
        acc[1][0] = MFMA(a1,b0,acc[1][0],0,0,0);
        acc[1][1] = MFMA(a1,b1,acc[1][1],0,0,0);
    }
    #pragma unroll
    for (int im=0; im<2; ++im)
    #pragma unroll
    for (int in=0; in<2; ++in){
        int col = n0 + in*16 + r;
        float bv = bias[col];
        #pragma unroll
        for (int r2=0; r2<4; ++r2){
            int row = m0 + rw*32 + im*16 + q*4 + r2;
            int bb = row >> 11, l = row & 2047;
            float v = siluf_(acc[im][in][r2] + bv);
            h[((size_t)(bb*L + l))*D + col] = v;
            h[((size_t)((2+bb)*L + (L-1-l)))*D + col] = v;
        }
    }
}

// ---------------- k_head: LN + in_proj + conv + x_proj + scan1, per 32-token chunk
// grid 256, block 256. Occupancy is grid-limited (1 block/CU) -> register hoists are free.
__global__ void __launch_bounds__(256,1)
k_head(const float* __restrict__ rIn,
       const float* __restrict__ lnw, const float* __restrict__ lnb,
       const ushort* __restrict__ wbi, const ushort* __restrict__ wbx,
       const float* __restrict__ cw, const float* __restrict__ cb,
       const float* __restrict__ Wdt, const float* __restrict__ bdt,
       const float* __restrict__ A_log,
       ushort* __restrict__ zh, ushort* __restrict__ xch,
       float* __restrict__ dtr, float* __restrict__ Bc, float* __restrict__ Cc,
       float* __restrict__ Ap, float* __restrict__ Bp, int blk){
    __shared__ ushort smHn[35*SHN];   // LN out: rows 0..31 owned, 32..34 halo
    __shared__ ushort smXm[35*SXM];   // xm bf16 (rows 32..34 = halo)
    __shared__ ushort smXc[32*SXM];   // conv out bf16
    __shared__ float  smDbc[32*68];   // xproj out
    const int tid = threadIdx.x;
    const int bi = blockIdx.x;
    const int s = bi >> 6, c = bi & 63;
    const int j = (s>>1)*3 + blk;
    const int base_tok = s*L + c*CH;

    // ---- hoisted per-thread params (latency overlaps LN/in_proj phases) ----
    float Ah[NS], wv[RK];
    {
        const float* ar = A_log + ((size_t)j*DI + tid)*NS;
        #pragma unroll
        for (int n=0;n<NS;++n) Ah[n] = ar[n];
        const float* wr = Wdt + ((size_t)j*DI + tid)*RK;
        #pragma unroll
        for (int r=0;r<RK;++r) wv[r] = wr[r];
    }
    const float bb2 = bdt[j*DI + tid];
    float cw0, cw1, cw2, cw3, cbb;
    {
        const float* w4 = cw + ((size_t)j*DI + tid)*4;
        cw0=w4[0]; cw1=w4[1]; cw2=w4[2]; cw3=w4[3];
        cbb = cb[j*DI + tid];
    }
    // ---- hoisted x_proj weight fragments (consumed after conv; loads hide under LN+in_proj) ----
    bfrag wX[8];
    {
        int w = tid>>6, lane = tid&63, q = lane>>4, r = lane&15;
        const ushort* bp = wbx + ((size_t)j*64 + w*16 + r)*256 + q*8;
        #pragma unroll
        for (int kb=0; kb<8; ++kb) wX[kb] = *(const bfrag*)(bp + kb*32);
    }

    // ---- LN (owned 32 tokens; 8 lanes/token; single-buffer read, no write) ----
    {
        int t = tid >> 3, g8 = tid & 7;
        size_t off = (size_t)(base_tok + t)*D + g8*16;
        float4 v[4];
        const float4* cp = (const float4*)(rIn + off);
        #pragma unroll
        for (int i=0;i<4;++i) v[i] = cp[i];
        float s1=0.f, s2=0.f;
        #pragma unroll
        for (int i=0;i<4;++i){
            s1 += v[i].x+v[i].y+v[i].z+v[i].w;
            s2 += v[i].x*v[i].x+v[i].y*v[i].y+v[i].z*v[i].z+v[i].w*v[i].w;
        }
        s1 += __shfl_xor(s1,1); s2 += __shfl_xor(s2,1);
        s1 += __shfl_xor(s1,2); s2 += __shfl_xor(s2,2);
        s1 += __shfl_xor(s1,4); s2 += __shfl_xor(s2,4);
        float mean = s1*(1.f/128.f);
        float var  = s2*(1.f/128.f) - mean*mean;
        float rstd = rsqrtf(var + 1e-5f);
        const float4* lwp = (const float4*)(lnw + j*D + g8*16);
        const float4* lbp = (const float4*)(lnb + j*D + g8*16);
        #pragma unroll
        for (int i=0;i<4;++i){
            float4 lw = lwp[i], lb = lbp[i];
            ushort4 o;
            o.x = f2bf((v[i].x-mean)*rstd*lw.x + lb.x);
            o.y = f2bf((v[i].y-mean)*rstd*lw.y + lb.y);
            o.z = f2bf((v[i].z-mean)*rstd*lw.z + lb.z);
            o.w = f2bf((v[i].w-mean)*rstd*lw.w + lb.w);
            *(ushort4*)&smHn[t*SHN + g8*16 + i*4] = o;
        }
    }
    // ---- halo LN (3 tokens, threads 0..23) ----
    if (c > 0 && tid < 24){
        int t = tid >> 3, g8 = tid & 7;
        size_t off = (size_t)(base_tok - 3 + t)*D + g8*16;
        float4 v[4];
        const float4* cp = (const float4*)(rIn + off);
        #pragma unroll
        for (int i=0;i<4;++i) v[i] = cp[i];
        float s1=0.f, s2=0.f;
        #pragma unroll
        for (int i=0;i<4;++i){
            s1 += v[i].x+v[i].y+v[i].z+v[i].w;
            s2 += v[i].x*v[i].x+v[i].y*v[i].y+v[i].z*v[i].z+v[i].w*v[i].w;
        }
        s1 += __shfl_xor(s1,1); s2 += __shfl_xor(s2,1);
        s1 += __shfl_xor(s1,2); s2 += __shfl_xor(s2,2);
        s1 += __shfl_xor(s1,4); s2 += __shfl_xor(s2,4);
        float mean = s1*(1.f/128.f);
        float var  = s2*(1.f/128.f) - mean*mean;
        float rstd = rsqrtf(var + 1e-5f);
        const float4* lwp = (const float4*)(lnw + j*D + g8*16);
        const float4* lbp = (const float4*)(lnb + j*D + g8*16);
        #pragma unroll
        for (int i=0;i<4;++i){
            float4 lw = lwp[i], lb = lbp[i];
            ushort4 o;
            o.x = f2bf((v[i].x-mean)*rstd*lw.x + lb.x);
            o.y = f2bf((v[i].y-mean)*rstd*lw.y + lb.y);
            o.z = f2bf((v[i].z-mean)*rstd*lw.z + lb.z);
            o.w = f2bf((v[i].w-mean)*rstd*lw.w + lb.w);
            *(ushort4*)&smHn[(32+t)*SHN + g8*16 + i*4] = o;
        }
    }
    __syncthreads();

    // ---- in_proj GEMM: M=48 (rows 32..47 halo tile, 3 valid), N=512, K=128; 4 waves x 128 cols ----
    {
        int w = tid>>6, lane = tid&63, q = lane>>4, r = lane&15;
        bfrag a[3][4];
        #pragma unroll
        for (int rt=0; rt<3; ++rt)
        #pragma unroll
        for (int kb=0; kb<4; ++kb)
            a[rt][kb] = *(bfrag*)&smHn[(rt*16 + r)*SHN + kb*32 + q*8];
        #pragma unroll
        for (int ct=0; ct<8; ++ct){
            int n0 = w*128 + ct*16;
            const ushort* bp = wbi + ((size_t)j*512 + n0 + r)*128 + q*8;
            facc a0 = {}, a1 = {}, a2 = {};
            #pragma unroll
            for (int kb=0; kb<4; ++kb){
                bfrag bv = *(const bfrag*)(bp + kb*32);
                a0 = MFMA(a[0][kb], bv, a0, 0,0,0);
                a1 = MFMA(a[1][kb], bv, a1, 0,0,0);
                a2 = MFMA(a[2][kb], bv, a2, 0,0,0);
            }
            int colL = n0 + r;
            if (colL < DI){
                #pragma unroll
                for (int r2=0;r2<4;++r2){
                    int rr = q*4 + r2;
                    smXm[rr*SXM + colL]      = f2bf(a0[r2]);
                    smXm[(16+rr)*SXM + colL] = f2bf(a1[r2]);
                    if (rr < 3) smXm[(32+rr)*SXM + colL] = f2bf(a2[r2]);
                }
            } else {
                int cz = colL - DI;
                #pragma unroll
                for (int r2=0;r2<4;++r2){
                    int rr = q*4 + r2;
                    zh[(size_t)(base_tok + rr)*DI + cz]      = f2bf(a0[r2]);
                    zh[(size_t)(base_tok + 16 + rr)*DI + cz] = f2bf(a1[r2]);
                }
            }
        }
    }
    __syncthreads();

    // ---- conv + silu (thread-per-d); bf16 to LDS + global ----
    {
        float xm1=0.f, xm2=0.f, xm3=0.f;
        if (c > 0){
            xm3 = bf2f(smXm[32*SXM + tid]);   // token -3
            xm2 = bf2f(smXm[33*SXM + tid]);   // token -2
            xm1 = bf2f(smXm[34*SXM + tid]);   // token -1
        }
        #pragma unroll 4
        for (int i=0;i<CH;++i){
            float x0 = bf2f(smXm[i*SXM + tid]);
            float v = siluf_(cbb + cw3*x0 + cw2*xm1 + cw1*xm2 + cw0*xm3);
            ushort vb = f2bf(v);
            smXc[i*SXM + tid] = vb;
            xch[(size_t)(base_tok+i)*DI + tid] = vb;
            xm3 = xm2; xm2 = xm1; xm1 = x0;
        }
    }
    __syncthreads();

    // ---- x_proj GEMM: M=32, N=64(pad40), K=256 (weights pre-hoisted in wX) ----
    {
        int w = tid>>6, lane = tid&63, q = lane>>4, r = lane&15;
        facc a0 = {}, a1 = {};
        #pragma unroll
        for (int kb=0; kb<8; ++kb){
            bfrag av0 = *(bfrag*)&smXc[r*SXM + kb*32 + q*8];
            bfrag av1 = *(bfrag*)&smXc[(16+r)*SXM + kb*32 + q*8];
            a0 = MFMA(av0, wX[kb], a0, 0,0,0);
            a1 = MFMA(av1, wX[kb], a1, 0,0,0);
        }
        int col = w*16 + r;
        #pragma unroll
        for (int r2=0;r2<4;++r2){
            int rr = q*4 + r2;
            smDbc[rr*68 + col]      = a0[r2];
            smDbc[(16+rr)*68 + col] = a1[r2];
            int row0 = base_tok + rr, row1 = base_tok + 16 + rr;
            if      (col < 8){  dtr[(size_t)row0*RK + col] = a0[r2];      dtr[(size_t)row1*RK + col] = a1[r2]; }
            else if (col < 24){ Bc [(size_t)row0*NS + (col-8)] = a0[r2];  Bc [(size_t)row1*NS + (col-8)] = a1[r2]; }
            else if (col < 40){ Cc [(size_t)row0*NS + (col-24)] = a0[r2]; Cc [(size_t)row1*NS + (col-24)] = a1[r2]; }
        }
    }
    __syncthreads();

    // ---- scan1: local chunk summary (thread-per-d); layout [chunk][d][16n] ----
    {
        float A[NS];
        #pragma unroll
        for (int n=0;n<NS;++n) A[n] = -__expf(Ah[n]);
        float ap[NS], hs[NS];
        #pragma unroll
        for (int n=0;n<NS;++n){ ap[n]=1.f; hs[n]=0.f; }
        #pragma unroll 4
        for (int l=0;l<CH;++l){
            float t = bb2;
            #pragma unroll
            for (int r=0;r<RK;++r) t += smDbc[l*68+r]*wv[r];
            float dtv = softplusf_(t);
            float xv  = bf2f(smXc[l*SXM + tid]);
            float dbx = dtv*xv;
            #pragma unroll
            for (int n=0;n<NS;++n){
                float dA = __expf(dtv*A[n]);
                ap[n] *= dA;
                hs[n] = dA*hs[n] + dbx*smDbc[l*68+8+n];
            }
        }
        size_t pb = (size_t)bi*4096 + (size_t)tid*16;
        #pragma unroll
        for (int k4=0;k4<4;++k4){
            float4 av, bv;
            av.x=ap[k4*4+0]; av.y=ap[k4*4+1]; av.z=ap[k4*4+2]; av.w=ap[k4*4+3];
            bv.x=hs[k4*4+0]; bv.y=hs[k4*4+1]; bv.z=hs[k4*4+2]; bv.w=hs[k4*4+3];
            *(float4*)&Ap[pb + k4*4] = av;
            *(float4*)&Bp[pb + k4*4] = bv;
        }
    }
}

// ---------------- scan mid: 4-way split per (stream, nd) lane + shfl stitch (proven round 7)
__global__ void __launch_bounds__(256,1)
k_scanmid(const float* __restrict__ Aprod, float* __restrict__ Bend){
    int g = blockIdx.x*256 + threadIdx.x;
    int q = g & 3;
    int lane2 = g >> 2;                 // 0..16383
    int ss = lane2 >> 12, nd = lane2 & 4095;
    size_t base = (size_t)ss*NCH*4096 + nd;
    float a[16], b[16];
    #pragma unroll
    for (int i=0;i<16;++i){
        a[i] = Aprod[base + (size_t)(q*16+i)*4096];
        b[i] = Bend [base + (size_t)(q*16+i)*4096];
    }
    float Aag = 1.f, Bag = 0.f;
    #pragma unroll
    for (int i=0;i<16;++i){ Bag = a[i]*Bag + b[i]; Aag *= a[i]; }
    int lid = threadIdx.x & 63, gb = lid & ~3;
    float hcar = 0.f;
    #pragma unroll
    for (int pq = 0; pq < 3; ++pq){
        float aA = __shfl(Aag, gb + pq, 64);
        float aB = __shfl(Bag, gb + pq, 64);
        if (pq < q) hcar = aA*hcar + aB;
    }
    #pragma unroll
    for (int i=0;i<16;++i){
        Bend[base + (size_t)(q*16+i)*4096] = hcar;   // carry INTO chunk q*16+i
        hcar = a[i]*hcar + b[i];
    }
}

// ---------------- k_tail: scan2 + gate + out_proj + residual add (rOut = proj + rIn)
// blk1's rOut IS the output rf/rb region (aliased); blk2 writes r3 (k_final combines).
__global__ void __launch_bounds__(256,1)
k_tail(const float* __restrict__ dtr, const ushort* __restrict__ xch,
       const float* __restrict__ Bc, const float* __restrict__ Cc,
       const float* __restrict__ A_log,
       const float* __restrict__ Wdt, const float* __restrict__ bdt,
       const float* __restrict__ h0, const ushort* __restrict__ zh,
       const float* __restrict__ Dp, const ushort* __restrict__ wbo,
       const float* __restrict__ rIn, float* __restrict__ rOut, int blk){
    int c = blockIdx.x, s = blockIdx.y; int j = (s>>1)*3 + blk;
    int d = threadIdx.x;
    __shared__ float sB[CH*NS], sC[CH*NS], sdtr[CH*RK];
    __shared__ ushort sg[CH*SXM];
    int base_tok = s*L + c*CH;
    int w = d>>6, lane = d&63, q = lane>>4, r = lane&15;
    // ---- hoisted out_proj weights (16 bfrags; latency hides under scan2) ----
    bfrag wB0[8], wB1[8];
    {
        const ushort* b0p = wbo + ((size_t)j*128 + w*32 + r)*256 + q*8;
        const ushort* b1p = b0p + 16*256;
        #pragma unroll
        for (int kb=0; kb<8; ++kb){
            wB0[kb] = *(const bfrag*)(b0p + kb*32);
            wB1[kb] = *(const bfrag*)(b1p + kb*32);
        }
    }
    // hoisted per-thread params
    float A[NS], wv[RK];
    {
        const float* ar = A_log + ((size_t)j*DI + d)*NS;
        #pragma unroll
        for (int n=0;n<NS;++n) A[n] = ar[n];
        const float* wr = Wdt + ((size_t)j*DI + d)*RK;
        #pragma unroll
        for (int r2=0;r2<RK;++r2) wv[r2] = wr[r2];
    }
    float bb = bdt[j*DI + d];
    float Dpd = Dp[j*DI + d];
    sB[d] = Bc[(size_t)base_tok*NS + d];
    sB[256+d] = Bc[(size_t)base_tok*NS + 256 + d];
    sC[d] = Cc[(size_t)base_tok*NS + d];
    sC[256+d] = Cc[(size_t)base_tok*NS + 256 + d];
    sdtr[d] = dtr[(size_t)base_tok*RK + d];
    #pragma unroll
    for (int n=0;n<NS;++n) A[n] = -__expf(A[n]);
    float hs[NS];
    {
        size_t pb = (size_t)(s*NCH + c)*4096 + (size_t)d*16;
        #pragma unroll
        for (int k4=0;k4<4;++k4){
            float4 v = *(const float4*)&h0[pb + k4*4];
            hs[k4*4+0]=v.x; hs[k4*4+1]=v.y; hs[k4*4+2]=v.z; hs[k4*4+3]=v.w;
        }
    }
    __syncthreads();
    #pragma unroll 4
    for (int l=0;l<CH;++l){
        float t = bb;
        #pragma unroll
        for (int r2=0;r2<RK;++r2) t += sdtr[l*RK+r2]*wv[r2];
        float dtv = softplusf_(t);
        float xv  = bf2f(xch[(size_t)(base_tok+l)*DI + d]);
        float dbx = dtv*xv;
        float p = 0.f;
        #pragma unroll
        for (int n=0;n<NS;++n){
            float dA = __expf(dtv*A[n]);
            hs[n] = dA*hs[n] + dbx*sB[l*NS+n];
            p += hs[n]*sC[l*NS+n];
        }
        float zv = bf2f(zh[(size_t)(base_tok+l)*DI + d]);
        sg[l*SXM + d] = f2bf((p + Dpd*xv)*siluf_(zv));
    }
    __syncthreads();
    // out_proj: M=32 (2 rt), N=128; wave w -> cols [w*32, w*32+32) (weights pre-hoisted)
    facc acc[2][2] = {};
    #pragma unroll
    for (int kb=0; kb<8; ++kb){
        bfrag av0 = *(bfrag*)&sg[r*SXM + kb*32 + q*8];
        bfrag av1 = *(bfrag*)&sg[(16+r)*SXM + kb*32 + q*8];
        acc[0][0] = MFMA(av0,wB0[kb],acc[0][0],0,0,0);
        acc[0][1] = MFMA(av0,wB1[kb],acc[0][1],0,0,0);
        acc[1][0] = MFMA(av1,wB0[kb],acc[1][0],0,0,0);
        acc[1][1] = MFMA(av1,wB1[kb],acc[1][1],0,0,0);
    }
    #pragma unroll
    for (int rt=0; rt<2; ++rt)
    #pragma unroll
    for (int ct=0; ct<2; ++ct){
        int col = w*32 + ct*16 + r;
        #pragma unroll
        for (int r2=0;r2<4;++r2){
            int row = base_tok + rt*16 + q*4 + r2;
            size_t i0 = (size_t)row*D + col;
            rOut[i0] = acc[rt][ct][r2] + rIn[i0];
        }
    }
}

// ---------------- final combine: out0 only (LDS transpose, coalesced writes)
__global__ void __launch_bounds__(256,1)
k_final(const float* __restrict__ r3, float* __restrict__ out){
    __shared__ float sf[128*33];
    int b = blockIdx.y, l0 = blockIdx.x*32;
    int tid = threadIdx.x;
    #pragma unroll
    for (int k=0;k<16;++k){
        int idx = tid + k*256;
        int l = l0 + (idx>>7), d = idx&127;
        int tf  = (b*L + l)*D + d;
        int tbk = ((2+b)*L + (L-1-l))*D + d;
        sf[d*33 + (l-l0)] = r3[tf] + r3[tbk];
    }
    __syncthreads();
    #pragma unroll
    for (int k=0;k<16;++k){
        int idx = tid + k*256;
        int d = idx>>5, li = idx&31;
        out[((size_t)(b*D + d))*L + l0 + li] = sf[d*33 + li];
    }
}

extern "C" void kernel_launch(void* const* d_in, const int* in_sizes, int n_in,
                              void* d_out, int out_size, void* d_ws, size_t ws_size,
                              hipStream_t stream){
    const float* x         = (const float*)d_in[0];
    const float* convd_w   = (const float*)d_in[1];
    const float* convd_b   = (const float*)d_in[2];
    const float* ln_w      = (const float*)d_in[3];
    const float* ln_b      = (const float*)d_in[4];
    const float* in_proj_w = (const float*)d_in[5];
    const float* conv_w    = (const float*)d_in[6];
    const float* conv_b    = (const float*)d_in[7];
    const float* xproj_w   = (const float*)d_in[8];
    const float* dtproj_w  = (const float*)d_in[9];
    const float* dtproj_b  = (const float*)d_in[10];
    const float* A_log     = (const float*)d_in[11];
    const float* Dparam    = (const float*)d_in[12];
    const float* outproj_w = (const float*)d_in[13];

    float* ws = (float*)d_ws;
    float* h     = ws; ws += SZ_D;   // residual into blk0
    float* r1    = ws; ws += SZ_D;   // residual into blk1 (= proj0 + h)
    float* r3    = ws; ws += SZ_D;   // final per-stream sum (= proj2 + r2)
    ushort* zh   = (ushort*)ws; ws += SZ_DI/2;   // bf16
    ushort* xch  = (ushort*)ws; ws += SZ_DI/2;   // bf16
    float* Ap    = ws; ws += SZ_D;   // [chunk][d][16n] summaries
    float* Bp    = ws; ws += SZ_D;   // summaries -> carries after scanmid
    float* dtr   = ws; ws += (size_t)TOK*RK;
    float* Bcv   = ws; ws += (size_t)TOK*NS;
    float* Ccv   = ws; ws += (size_t)TOK*NS;
    ushort* wall = (ushort*)ws;
    ushort* wbi  = wall;
    ushort* wbo  = wall + 393216;
    ushort* wbx  = wall + 589824;

    // r2 (residual into blk2, == rf/rb output) lives directly in the output buffer.
    float* r2p  = (float*)d_out + (size_t)2*D*L;

    k_downcvt<<<256, 256, 0, stream>>>(x, convd_w, convd_b, in_proj_w, outproj_w,
                                       xproj_w, h, wall);

    const float* rin[3]  = { h,  r1,  r2p };
    float*       rout[3] = { r1, r2p, r3  };
    for (int blk = 0; blk < 3; ++blk){
        k_head<<<NSTREAM*NCH, 256, 0, stream>>>(rin[blk], ln_w, ln_b, wbi, wbx,
                                                conv_w, conv_b, dtproj_w, dtproj_b, A_log,
                                                zh, xch, dtr, Bcv, Ccv, Ap, Bp, blk);
        k_scanmid<<<256, 256, 0, stream>>>(Ap, Bp);
        k_tail<<<dim3(NCH, NSTREAM), 256, 0, stream>>>(dtr, xch, Bcv, Ccv, A_log,
                                                       dtproj_w, dtproj_b, Bp, zh,
                                                       Dparam, wbo, rin[blk], rout[blk], blk);
    }

    k_final<<<dim3(NCH, B), 256, 0, stream>>>(r3, (float*)d_out);
}